// Round 5
// baseline (3531.472 us; speedup 1.0000x reference)
//
#include <hip/hip_runtime.h>

typedef unsigned short u16;
typedef unsigned int u32;

#define NPTS 131072
#define CD 128
#define KOFF 27
#define MMAP 65536
#define TOTE (KOFF * MMAP)  // 1769472 entries (< 2^21)
#define LDAB 136            // LDS row stride (u16) for A/B tiles
#define TR 128              // output rows per fused block
#define NTILE (NPTS / TR)   // 1024 blocks
#define MAXE 2560           // max entries per tile (avg 1728, sigma ~42)
#define ACCP 132            // f32 stride for LDS accumulator

__device__ __forceinline__ u16 f2bf(float f) {  // f32 -> bf16 RNE
  u32 u = __float_as_uint(f);
  u32 r = (u + 0x7fffu + ((u >> 16) & 1u)) >> 16;
  return (u16)r;
}

typedef __attribute__((ext_vector_type(8))) short bf16x8;
typedef __attribute__((ext_vector_type(4))) float f32x4;

// ---------------- dtype conversion ----------------
__global__ __launch_bounds__(256) void k_convert_x(const float* __restrict__ x,
                                                   u16* __restrict__ xb) {
  long i = ((long)blockIdx.x * 256 + threadIdx.x) * 8;
  float4 a = *(const float4*)(x + i);
  float4 b = *(const float4*)(x + i + 4);
  uint4 v;
  v.x = f2bf(a.x) | ((u32)f2bf(a.y) << 16);
  v.y = f2bf(a.z) | ((u32)f2bf(a.w) << 16);
  v.z = f2bf(b.x) | ((u32)f2bf(b.y) << 16);
  v.w = f2bf(b.z) | ((u32)f2bf(b.w) << 16);
  *(uint4*)(xb + i) = v;
}

// W [K][ci][co] f32 -> Wb [K][co][ci] bf16
__global__ __launch_bounds__(256) void k_convert_w(const float* __restrict__ W,
                                                   u16* __restrict__ Wb) {
  int idx = blockIdx.x * 256 + threadIdx.x;
  if (idx >= KOFF * 2048) return;
  int k = idx >> 11;
  int rem = idx & 2047;
  int co = rem >> 4;
  int cc = rem & 15;
  const float* ws = W + (long)k * (CD * CD) + (long)(cc * 8) * CD + co;
  u16 t[8];
#pragma unroll
  for (int j = 0; j < 8; ++j) t[j] = f2bf(ws[j * CD]);
  uint4 v;
  v.x = t[0] | ((u32)t[1] << 16);
  v.y = t[2] | ((u32)t[3] << 16);
  v.z = t[4] | ((u32)t[5] << 16);
  v.w = t[6] | ((u32)t[7] << 16);
  ((uint4*)Wb)[idx] = v;
}

// ---------------- counting sort by output row ----------------
__global__ __launch_bounds__(256) void k_hist(const int* __restrict__ mo,
                                              u32* __restrict__ hist) {
  int i = blockIdx.x * 256 + threadIdx.x;
  atomicAdd(&hist[mo[i]], 1u);
}

__global__ __launch_bounds__(256) void k_scanA(const u32* __restrict__ hist,
                                               u32* __restrict__ offs,
                                               u32* __restrict__ bsum) {
  __shared__ u32 sh[256];
  int t = threadIdx.x, b = blockIdx.x, i = b * 256 + t;
  u32 v = hist[i];
  u32 run = v;
  sh[t] = run;
  __syncthreads();
  for (int d = 1; d < 256; d <<= 1) {
    u32 y = (t >= d) ? sh[t - d] : 0u;
    __syncthreads();
    run += y;
    sh[t] = run;
    __syncthreads();
  }
  offs[i] = run - v;
  if (t == 255) bsum[b] = run;
}

__global__ __launch_bounds__(512) void k_scanB(u32* __restrict__ bsum) {
  __shared__ u32 sh[512];
  int t = threadIdx.x;
  u32 v = bsum[t];
  u32 run = v;
  sh[t] = run;
  __syncthreads();
  for (int d = 1; d < 512; d <<= 1) {
    u32 y = (t >= d) ? sh[t - d] : 0u;
    __syncthreads();
    run += y;
    sh[t] = run;
    __syncthreads();
  }
  bsum[t] = run - v;
}

__global__ __launch_bounds__(256) void k_scanC(u32* __restrict__ offs,
                                               const u32* __restrict__ bsum) {
  int t = threadIdx.x, b = blockIdx.x, i = b * 256 + t;
  offs[i] += bsum[b];
  if (i == 0) offs[NPTS] = TOTE;
}

// perm[p] = entry id | (tile-local row << 21), sorted by output row
__global__ __launch_bounds__(256) void k_place(const int* __restrict__ mo,
                                               const u32* __restrict__ offs,
                                               u32* __restrict__ cur,
                                               u32* __restrict__ perm) {
  int i = blockIdx.x * 256 + threadIdx.x;
  int o = mo[i];
  u32 p = offs[o] + atomicAdd(&cur[o], 1u);
  perm[p] = (u32)i | ((u32)(o & (TR - 1)) << 21);
}

// ---------------- fused scatter-GEMM + BN-stats: one block per 128-row output tile ------------
__global__ __launch_bounds__(512, 1) void k_fused(const u16* __restrict__ src,
                                                  const u16* __restrict__ Wb,
                                                  const int* __restrict__ mi,
                                                  const u32* __restrict__ perm,
                                                  const u32* __restrict__ offs,
                                                  u32* __restrict__ accb,
                                                  float* __restrict__ stats) {
  __shared__ float accL[TR * ACCP];      // 67584 B
  __shared__ u16 As[64 * LDAB];          // 17408 B
  __shared__ u16 Bs[128 * LDAB];         // 34816 B
  __shared__ u32 sidS[MAXE];             // 10240 B  (sorted by k: id | lrow<<21)
  __shared__ u32 sinp[MAXE];             // 10240 B  (raw ids, then input rows)
  __shared__ u32 kcntS[32], koffS[32], kcurS[32];

  const int t = threadIdx.x;
  const int tile = blockIdx.x;
  const u32 s0 = offs[tile * TR];
  const u32 s1 = offs[tile * TR + TR];
  int n = (int)(s1 - s0);
  if (n > MAXE) n = MAXE;  // safety clamp (never hit for uniform maps)

  // zero acc + k-counters
  for (int i = t; i < TR * ACCP; i += 512) accL[i] = 0.f;
  if (t < 32) kcntS[t] = 0;
  __syncthreads();

  // pass 1: load ids, histogram k
  for (int i = t; i < n; i += 512) {
    u32 p = perm[s0 + i];
    sinp[i] = p;
    atomicAdd(&kcntS[(p & 0x1FFFFFu) >> 16], 1u);
  }
  __syncthreads();
  if (t == 0) {
    u32 r = 0;
    for (int j = 0; j < KOFF; ++j) {
      koffS[j] = r;
      r += kcntS[j];
    }
  }
  __syncthreads();
  if (t < KOFF) kcurS[t] = koffS[t];
  __syncthreads();
  // pass 2: scatter into k-sorted order
  for (int i = t; i < n; i += 512) {
    u32 p = sinp[i];
    u32 pos = atomicAdd(&kcurS[(p & 0x1FFFFFu) >> 16], 1u);
    sidS[pos] = p;
  }
  __syncthreads();
  // pass 3: fetch input rows for sorted entries
  for (int i = t; i < n; i += 512) sinp[i] = (u32)mi[sidS[i] & 0x1FFFFFu];
  __syncthreads();

  const int wave = t >> 6, lane = t & 63;
  const int lr = lane & 15, quad = lane >> 4;
  const int wr = (wave & 3) * 16;   // 4 row-groups of 16
  const int wc = (wave >> 2) * 64;  // 2 col-groups of 64

  for (int k = 0; k < KOFF; ++k) {
    const int nk = (int)kcntS[k];
    if (!nk) continue;
    __syncthreads();  // prior MFMA done reading As/Bs
    // stage B_k: 128 rows x 128 cols bf16
    const uint4* wsrc = (const uint4*)(Wb + (long)k * (CD * CD));
    for (int q = t; q < 2048; q += 512) {
      int co = q >> 4, cc = q & 15;
      *(uint4*)&Bs[co * LDAB + cc * 8] = wsrc[q];
    }
    const int kb = (int)koffS[k];
    for (int b0 = 0; b0 < nk; b0 += 64) {
      if (b0) __syncthreads();  // prior MFMA done reading As
      const int nv = (nk - b0 < 64) ? (nk - b0) : 64;
      // stage A batch: 64 gathered rows
      for (int q = t; q < 1024; q += 512) {
        int r = q >> 4, cc = q & 15;
        int idx = (r < nv) ? (kb + b0 + r) : kb;
        long row = sinp[idx];
        *(uint4*)&As[r * LDAB + cc * 8] = ((const uint4*)(src + row * CD))[cc];
      }
      __syncthreads();
      // MFMA: each wave computes 16x64 of the 64x128 C batch
      f32x4 acc[4] = {};
#pragma unroll
      for (int kk = 0; kk < 4; ++kk) {
        bf16x8 a = *(const bf16x8*)&As[(wr + lr) * LDAB + (kk * 4 + quad) * 8];
        bf16x8 bfr[4];
#pragma unroll
        for (int nt = 0; nt < 4; ++nt)
          bfr[nt] = *(const bf16x8*)&Bs[(wc + nt * 16 + lr) * LDAB + (kk * 4 + quad) * 8];
#pragma unroll
        for (int nt = 0; nt < 4; ++nt)
          acc[nt] = __builtin_amdgcn_mfma_f32_16x16x32_bf16(a, bfr[nt], acc[nt], 0, 0, 0);
      }
      // scatter-add into LDS accumulator (C/D: col=lane&15, row=quad*4+v)
#pragma unroll
      for (int v = 0; v < 4; ++v) {
        int slot = wr + quad * 4 + v;
        if (slot < nv) {
          int lrow = (int)(sidS[kb + b0 + slot] >> 21);
          float* arow = accL + lrow * ACCP;
#pragma unroll
          for (int nt = 0; nt < 4; ++nt)
            atomicAdd(&arow[wc + nt * 16 + lr], acc[nt][v]);
        }
      }
    }
  }
  __syncthreads();

  // epilogue: write bf16 accb + fused BN stats
  for (int i = t; i < TR * 64; i += 512) {
    int row = i >> 6, cp = i & 63;
    float lo = accL[row * ACCP + cp * 2];
    float hi = accL[row * ACCP + cp * 2 + 1];
    accb[((size_t)(tile * TR + row)) * 64 + cp] = (u32)f2bf(lo) | ((u32)f2bf(hi) << 16);
  }
  int c = t & 127, g = t >> 7;
  float s = 0.f, s2 = 0.f;
  for (int r = g; r < TR; r += 4) {
    float v = accL[r * ACCP + c];
    s += v;
    s2 += v * v;
  }
  float* fbuf = (float*)As;  // reuse (main loop done)
  fbuf[t] = s;
  fbuf[512 + t] = s2;
  __syncthreads();
  if (t < 128) {
    float ss = fbuf[t] + fbuf[t + 128] + fbuf[t + 256] + fbuf[t + 384];
    float ss2 = fbuf[512 + t] + fbuf[512 + t + 128] + fbuf[512 + t + 256] + fbuf[512 + t + 384];
    atomicAdd(&stats[t], ss);
    atomicAdd(&stats[128 + t], ss2);
  }
}

// ---------------- BN finalize / apply ----------------
__global__ void k_finalize(const float* __restrict__ stats, const float* __restrict__ gamma,
                           const float* __restrict__ beta, float* __restrict__ scsh) {
  int c = threadIdx.x;
  float mean = stats[c] * (1.f / NPTS);
  float var = stats[128 + c] * (1.f / NPTS) - mean * mean;
  float sc = rsqrtf(var + 1e-5f) * gamma[c];
  scsh[c] = sc;
  scsh[128 + c] = beta[c] - mean * sc;
}

__device__ __forceinline__ float elu(float v) { return v > 0.f ? v : expf(v) - 1.f; }

__global__ __launch_bounds__(256) void k_apply_mid(const u16* __restrict__ accb,
                                                   const float* __restrict__ scsh,
                                                   u16* __restrict__ y) {
  long i = ((long)blockIdx.x * 256 + threadIdx.x) * 8;
  int c = (int)(i & 127);
  uint4 a = *(const uint4*)(accb + i);
  u32 w[4] = {a.x, a.y, a.z, a.w};
  u32 ov[4];
#pragma unroll
  for (int j = 0; j < 4; ++j) {
    float lo = __uint_as_float(w[j] << 16);
    float hi = __uint_as_float(w[j] & 0xffff0000u);
    float r0 = elu(lo * scsh[c + 2 * j] + scsh[128 + c + 2 * j]);
    float r1 = elu(hi * scsh[c + 2 * j + 1] + scsh[129 + c + 2 * j]);
    ov[j] = (u32)f2bf(r0) | ((u32)f2bf(r1) << 16);
  }
  uint4 o = {ov[0], ov[1], ov[2], ov[3]};
  *(uint4*)(y + i) = o;
}

__global__ __launch_bounds__(256) void k_apply_final(const u16* __restrict__ accb,
                                                     const float* __restrict__ scsh,
                                                     const float* __restrict__ x,
                                                     float* __restrict__ out) {
  long i = ((long)blockIdx.x * 256 + threadIdx.x) * 8;
  int c = (int)(i & 127);
  uint4 a = *(const uint4*)(accb + i);
  u32 w[4] = {a.x, a.y, a.z, a.w};
  float4 rx0 = *(const float4*)(x + i);
  float4 rx1 = *(const float4*)(x + i + 4);
  float rx[8] = {rx0.x, rx0.y, rx0.z, rx0.w, rx1.x, rx1.y, rx1.z, rx1.w};
  float res[8];
#pragma unroll
  for (int j = 0; j < 4; ++j) {
    float lo = __uint_as_float(w[j] << 16);
    float hi = __uint_as_float(w[j] & 0xffff0000u);
    res[2 * j] = elu(lo * scsh[c + 2 * j] + scsh[128 + c + 2 * j] + rx[2 * j]);
    res[2 * j + 1] = elu(hi * scsh[c + 2 * j + 1] + scsh[129 + c + 2 * j] + rx[2 * j + 1]);
  }
  float4 o0 = {res[0], res[1], res[2], res[3]};
  float4 o1 = {res[4], res[5], res[6], res[7]};
  *(float4*)(out + i) = o0;
  *(float4*)(out + i + 4) = o1;
}

// ---------------- host ----------------
extern "C" void kernel_launch(void* const* d_in, const int* in_sizes, int n_in,
                              void* d_out, int out_size, void* d_ws, size_t ws_size,
                              hipStream_t stream) {
  const float* x = (const float*)d_in[0];
  const float* W1 = (const float*)d_in[1];
  const float* g1 = (const float*)d_in[2];
  const float* b1 = (const float*)d_in[3];
  const float* W2 = (const float*)d_in[4];
  const float* g2 = (const float*)d_in[5];
  const float* b2 = (const float*)d_in[6];
  const int* m1i = (const int*)d_in[7];
  const int* m1o = (const int*)d_in[8];
  const int* m2i = (const int*)d_in[9];
  const int* m2o = (const int*)d_in[10];
  float* out = (float*)d_out;

  char* base = (char*)d_ws;
  size_t off = 0;
  auto alloc = [&](size_t bytes) -> void* {
    void* r = base + off;
    off = (off + bytes + 255) & ~(size_t)255;
    return r;
  };
  u16* xb = (u16*)alloc((size_t)NPTS * CD * 2);
  u16* yb = (u16*)alloc((size_t)NPTS * CD * 2);
  u16* Wb1 = (u16*)alloc((size_t)KOFF * CD * CD * 2);
  u16* Wb2 = (u16*)alloc((size_t)KOFF * CD * CD * 2);
  u32* accb = (u32*)alloc((size_t)NPTS * 64 * 4);
  // contiguous memset region: hist, cur, stats
  u32* hist = (u32*)alloc((size_t)NPTS * 4);
  u32* cur = (u32*)alloc((size_t)NPTS * 4);
  float* stats = (float*)alloc(256 * 4);
  size_t msSize = (size_t)((char*)base + off - (char*)hist);
  u32* offs = (u32*)alloc(((size_t)NPTS + 1) * 4);
  float* scsh = (float*)alloc(256 * 4);
  u32* bsum = (u32*)alloc(512 * 4);
  u32* perm = (u32*)alloc((size_t)TOTE * 4);

  k_convert_x<<<(NPTS * CD) / 2048, 256, 0, stream>>>(x, xb);
  k_convert_w<<<(KOFF * 2048 + 255) / 256, 256, 0, stream>>>(W1, Wb1);
  k_convert_w<<<(KOFF * 2048 + 255) / 256, 256, 0, stream>>>(W2, Wb2);

  const int EB = TOTE / 256;

  auto run_conv = [&](const u16* srcm, const u16* Wbm, const int* mi, const int* mo) {
    hipMemsetAsync(hist, 0, msSize, stream);
    k_hist<<<EB, 256, 0, stream>>>(mo, hist);
    k_scanA<<<512, 256, 0, stream>>>(hist, offs, bsum);
    k_scanB<<<1, 512, 0, stream>>>(bsum);
    k_scanC<<<512, 256, 0, stream>>>(offs, bsum);
    k_place<<<EB, 256, 0, stream>>>(mo, offs, cur, perm);
    k_fused<<<NTILE, 512, 0, stream>>>(srcm, Wbm, mi, perm, offs, accb, stats);
  };

  run_conv(xb, Wb1, m1i, m1o);
  k_finalize<<<1, 128, 0, stream>>>(stats, g1, b1, scsh);
  k_apply_mid<<<(NPTS * CD) / 2048, 256, 0, stream>>>((const u16*)accb, scsh, yb);

  run_conv(yb, Wb2, m2i, m2o);
  k_finalize<<<1, 128, 0, stream>>>(stats, g2, b2, scsh);
  k_apply_final<<<(NPTS * CD) / 2048, 256, 0, stream>>>((const u16*)accb, scsh, x, out);
}